// Round 6
// baseline (75.977 us; speedup 1.0000x reference)
//
#include <hip/hip_runtime.h>
#include <math.h>

#define N_OCT  32
#define N_SMP  32768
#define N_PAIR 64          // B*E = 4*16
#define BPP    16          // blocks per pair: 2048 samples/block, 8/thread

typedef float v2f __attribute__((ext_vector_type(2)));

// ---------------------------------------------------------------------------
// Kernel 1: oscillator bank, rotation-recurrence form.
//  Prologue (lanes 0-31): recompute pair's (w,a) with the reference's EXACT
//   sequential fp32 cumsum rounding; w pre-divided by 2pi (revolutions).
//   Also precompute per-octave rotation unit vector (C,S) = cos/sin(256*w).
//   LDS holds float4 (w, a, C, S) per octave.
//  Body: 8 samples/thread strided 256. Per octave: one hw sin+cos at the
//   base phase, then 7 rotation steps (v_pk_mul + v_pk_fma + acc fma each).
//   Rotation phase deviation <= ~1e-4 rad, an order below the ~2e-3 rad
//   fp32 phase-quantization noise shared (uncorrelated) with the reference.
//  Epilogue: block max -> plain store (kernel boundary is the sync; R4
//   showed per-block device-scope fences cost ~420us).
// ---------------------------------------------------------------------------
__global__ __launch_bounds__(256) void f0res_osc(
    const float* __restrict__ f0_in,
    const float* __restrict__ dec_in,
    const float* __restrict__ fs_in,
    float* __restrict__ out,
    float* __restrict__ bmax)        // [N_PAIR][BPP]
{
    __shared__ __align__(16) float4 sp[N_OCT];   // (w_rev, amp, C, S)

    const int pair = blockIdx.x >> 4;
    const int blk  = blockIdx.x & (BPP - 1);
    const int tid  = threadIdx.x;

    // ---- in-block setup (lanes 0-31 of wave 0) ----
    if (tid < N_OCT) {
        const float minf   = (float)(20.0 / 11025.0);
        const float frange = (float)(3000.0 / 11025.0 - 20.0 / 11025.0);
        const float pif    = 3.14159265358979323846f;
        const float INV2PI = 0.15915494309189535f;

        float f0 = fabsf(f0_in[pair]);
        float fs = fs_in[pair];
        float x  = dec_in[pair];

        float s1 = 1.0f / (1.0f + expf(-x));      // double sigmoid (ref quirk)
        float s2 = 1.0f / (1.0f + expf(-s1));
        float d  = 0.01f + s2 * (float)(0.99 * 0.99);
        float ld = logf(d + 1e-12f);
        float f0p = (minf + f0 * frange) * pif;

        // sequential fp32 cumsums — bit-match the reference rounding order
        float fac = 0.0f, acl = 0.0f, myfac = 0.0f, myacl = 0.0f;
#pragma unroll
        for (int o = 0; o < N_OCT; ++o) {
            fac += fs;
            acl += ld;
            if (o == tid) { myfac = fac; myacl = acl; }
        }
        float f0s = f0p * myfac;
        float w   = (f0s < 1.0f) ? f0s * INV2PI : 0.0f;  // revolutions/sample
        float dd  = __builtin_amdgcn_fractf(w * 256.0f); // rotation step phase
        sp[tid] = make_float4(w, expf(myacl),
                              __builtin_amdgcn_cosf(dd),
                              __builtin_amdgcn_sinf(dd));
    }
    __syncthreads();

    const int   s0 = (blk << 11) + tid;          // samples s0 + 256*k, k=0..7
    const float t0 = (float)(s0 + 1);            // t = s+1, exact in fp32

    float acc[8] = {0,0,0,0,0,0,0,0};
    const float4* p4 = (const float4*)sp;
#pragma unroll
    for (int o = 0; o < N_OCT; ++o) {
        float4 prm = p4[o];                      // ds_read_b128, broadcast
        const float w = prm.x, a = prm.y;
        const v2f C2 = { prm.z, prm.z };
        const v2f S2 = { prm.w, prm.w };

        float r0 = __builtin_amdgcn_fractf(w * t0);
        v2f sc = { __builtin_amdgcn_sinf(r0), __builtin_amdgcn_cosf(r0) };
        acc[0] = fmaf(a, sc.x, acc[0]);
#pragma unroll
        for (int k = 1; k < 8; ++k) {
            v2f tmp = { sc.y, -sc.x };           // (c, -s)
            sc = __builtin_elementwise_fma(sc, C2, tmp * S2);  // pk_fma + pk_mul
            acc[k] = fmaf(a, sc.x, acc[k]);
        }
    }

    float* op = out + pair * N_SMP + s0;
#pragma unroll
    for (int k = 0; k < 8; ++k) op[k * 256] = acc[k];

    // ---- block max -> one plain store (no atomics, no init needed) ----
    float av_ = 0.0f;
#pragma unroll
    for (int k = 0; k < 8; ++k) av_ = fmaxf(av_, fabsf(acc[k]));
#pragma unroll
    for (int m = 32; m >= 1; m >>= 1)
        av_ = fmaxf(av_, __shfl_xor(av_, m, 64));
    __shared__ float wm[4];
    if ((tid & 63) == 0) wm[tid >> 6] = av_;
    __syncthreads();
    if (tid == 0)
        bmax[pair * BPP + blk] = fmaxf(fmaxf(wm[0], wm[1]), fmaxf(wm[2], wm[3]));
}

// ---------------------------------------------------------------------------
// Kernel 2: reduce the 16 per-block maxes, then normalize (float4, L2-hot).
// ---------------------------------------------------------------------------
__global__ __launch_bounds__(256) void f0res_norm(
    float* __restrict__ out, const float* __restrict__ bmax)
{
    const int pair = blockIdx.x >> 5;                   // 32 blocks per pair
    const int tid  = threadIdx.x;

    float v = (tid < BPP) ? bmax[pair * BPP + tid] : 0.0f;
#pragma unroll
    for (int m = 8; m >= 1; m >>= 1)
        v = fmaxf(v, __shfl_xor(v, m, 64));
    __shared__ float smx;
    if (tid == 0) smx = v;
    __syncthreads();
    const float inv = 1.0f / (smx + 1e-8f);

    const int idx = ((blockIdx.x & 31) << 8) + tid;     // 256 float4 per block
    float4* o4 = (float4*)(out + pair * N_SMP);
    float4 val = o4[idx];
    val.x *= inv; val.y *= inv; val.z *= inv; val.w *= inv;
    o4[idx] = val;
}

extern "C" void kernel_launch(void* const* d_in, const int* in_sizes, int n_in,
                              void* d_out, int out_size, void* d_ws, size_t ws_size,
                              hipStream_t stream) {
    const float* f0  = (const float*)d_in[0];
    const float* dec = (const float*)d_in[1];
    const float* fs  = (const float*)d_in[2];
    float* out = (float*)d_out;

    float* bmax = (float*)d_ws;                 // 64*16 floats

    f0res_osc <<<N_PAIR * BPP, 256, 0, stream>>>(f0, dec, fs, out, bmax);
    f0res_norm<<<N_PAIR * 32,  256, 0, stream>>>(out, bmax);
}

// Round 7
// 73.118 us; speedup vs baseline: 1.0391x; 1.0391x over previous
//
#include <hip/hip_runtime.h>
#include <math.h>

#define N_OCT  32
#define N_SMP  32768
#define N_PAIR 64          // B*E = 4*16
#define BPP    32          // blocks per pair: 1024 samples/block, 4/thread

// ---------------------------------------------------------------------------
// Kernel 1: oscillator bank (best-measured variant, R5 form).
//  Prologue (lanes 0-31): recompute pair's (w,a) with the reference's EXACT
//   sequential fp32 cumsum rounding (lane o captures the running sum at
//   step o). w stored pre-divided by 2pi (revolutions) so the body is
//   mul + v_fract + v_sin + v_fma per octave-sample.
//  Body: 4 samples/thread (4 independent FMA chains for ILP — R6 showed a
//   serial rotation recurrence is NOT faster despite fewer issued ops).
//  Epilogue: block max -> plain store. Kernel boundary is the sync; R4
//   showed per-block device-scope fences cost ~420us.
// ---------------------------------------------------------------------------
__global__ __launch_bounds__(256) void f0res_osc(
    const float* __restrict__ f0_in,
    const float* __restrict__ dec_in,
    const float* __restrict__ fs_in,
    float* __restrict__ out,
    float* __restrict__ bmax)        // [N_PAIR][BPP]
{
    __shared__ __align__(16) float sw[N_OCT];
    __shared__ __align__(16) float sa[N_OCT];

    const int pair = blockIdx.x >> 5;
    const int blk  = blockIdx.x & (BPP - 1);
    const int tid  = threadIdx.x;

    // ---- in-block setup (lanes 0-31 of wave 0) ----
    if (tid < N_OCT) {
        const float minf   = (float)(20.0 / 11025.0);
        const float frange = (float)(3000.0 / 11025.0 - 20.0 / 11025.0);
        const float pif    = 3.14159265358979323846f;
        const float INV2PI = 0.15915494309189535f;

        float f0 = fabsf(f0_in[pair]);
        float fs = fs_in[pair];
        float x  = dec_in[pair];

        float s1 = 1.0f / (1.0f + expf(-x));      // double sigmoid (ref quirk)
        float s2 = 1.0f / (1.0f + expf(-s1));
        float d  = 0.01f + s2 * (float)(0.99 * 0.99);
        float ld = logf(d + 1e-12f);
        float f0p = (minf + f0 * frange) * pif;

        // sequential fp32 cumsums — bit-match the reference rounding order
        float fac = 0.0f, acl = 0.0f, myfac = 0.0f, myacl = 0.0f;
#pragma unroll
        for (int o = 0; o < N_OCT; ++o) {
            fac += fs;
            acl += ld;
            if (o == tid) { myfac = fac; myacl = acl; }
        }
        float f0s = f0p * myfac;
        sw[tid] = (f0s < 1.0f) ? f0s * INV2PI : 0.0f;   // Nyquist mask; sin(0)=0
        sa[tid] = expf(myacl);                          // d^(o+1)
    }
    __syncthreads();

    // preload (w,a): 16 x ds_read_b128 same-address broadcast (conflict-free)
    float4 wv[8], av[8];
    const float4* w4 = (const float4*)sw;
    const float4* a4 = (const float4*)sa;
#pragma unroll
    for (int i = 0; i < 8; ++i) { wv[i] = w4[i]; av[i] = a4[i]; }

    const int   s0 = (blk << 10) + tid;         // samples s0 + {0,256,512,768}
    const float t0 = (float)(s0 + 1);           // t = s+1, exact in fp32
    const float t1 = (float)(s0 + 257);
    const float t2 = (float)(s0 + 513);
    const float t3 = (float)(s0 + 769);

    float acc0 = 0.0f, acc1 = 0.0f, acc2 = 0.0f, acc3 = 0.0f;
#pragma unroll
    for (int i = 0; i < 8; ++i) {
        const float wr[4] = { wv[i].x, wv[i].y, wv[i].z, wv[i].w };
        const float ar[4] = { av[i].x, av[i].y, av[i].z, av[i].w };
#pragma unroll
        for (int j = 0; j < 4; ++j) {
            float w = wr[j], a = ar[j];
            acc0 = fmaf(a, __builtin_amdgcn_sinf(__builtin_amdgcn_fractf(w * t0)), acc0);
            acc1 = fmaf(a, __builtin_amdgcn_sinf(__builtin_amdgcn_fractf(w * t1)), acc1);
            acc2 = fmaf(a, __builtin_amdgcn_sinf(__builtin_amdgcn_fractf(w * t2)), acc2);
            acc3 = fmaf(a, __builtin_amdgcn_sinf(__builtin_amdgcn_fractf(w * t3)), acc3);
        }
    }

    float* op = out + pair * N_SMP + s0;
    op[0]   = acc0;
    op[256] = acc1;
    op[512] = acc2;
    op[768] = acc3;

    // ---- block max -> one plain store (no atomics, no init needed) ----
    float av_ = fmaxf(fmaxf(fabsf(acc0), fabsf(acc1)),
                      fmaxf(fabsf(acc2), fabsf(acc3)));
#pragma unroll
    for (int m = 32; m >= 1; m >>= 1)
        av_ = fmaxf(av_, __shfl_xor(av_, m, 64));
    __shared__ float wm[4];
    if ((tid & 63) == 0) wm[tid >> 6] = av_;
    __syncthreads();
    if (tid == 0)
        bmax[pair * BPP + blk] = fmaxf(fmaxf(wm[0], wm[1]), fmaxf(wm[2], wm[3]));
}

// ---------------------------------------------------------------------------
// Kernel 2: reduce the 32 per-block maxes, then normalize (float4, L2-hot).
// ---------------------------------------------------------------------------
__global__ __launch_bounds__(256) void f0res_norm(
    float* __restrict__ out, const float* __restrict__ bmax)
{
    const int pair = blockIdx.x >> 5;                   // 32 blocks per pair
    const int tid  = threadIdx.x;

    float v = (tid < BPP) ? bmax[pair * BPP + tid] : 0.0f;
#pragma unroll
    for (int m = 16; m >= 1; m >>= 1)
        v = fmaxf(v, __shfl_xor(v, m, 64));
    __shared__ float smx;
    if (tid == 0) smx = v;
    __syncthreads();
    const float inv = 1.0f / (smx + 1e-8f);

    const int idx = ((blockIdx.x & 31) << 8) + tid;     // 256 float4 per block
    float4* o4 = (float4*)(out + pair * N_SMP);
    float4 val = o4[idx];
    val.x *= inv; val.y *= inv; val.z *= inv; val.w *= inv;
    o4[idx] = val;
}

extern "C" void kernel_launch(void* const* d_in, const int* in_sizes, int n_in,
                              void* d_out, int out_size, void* d_ws, size_t ws_size,
                              hipStream_t stream) {
    const float* f0  = (const float*)d_in[0];
    const float* dec = (const float*)d_in[1];
    const float* fs  = (const float*)d_in[2];
    float* out = (float*)d_out;

    float* bmax = (float*)d_ws;                 // 64*32 floats

    f0res_osc <<<N_PAIR * BPP, 256, 0, stream>>>(f0, dec, fs, out, bmax);
    f0res_norm<<<N_PAIR * 32,  256, 0, stream>>>(out, bmax);
}